// Round 12
// baseline (127.457 us; speedup 1.0000x reference)
//
#include <hip/hip_runtime.h>

// MHA forward, MI355X gfx950. bf16 MFMA pipeline, fp32 accumulate.
// Stages: cvt(fp32->bf16) -> fused QKV gemm_bt -> flash attention v12
//         (8-wave 256-q blocks, shared 3-buf KV stream, 32x32 MFMA,
//          in-register softmax via cvt_pk + permlane32_swap) -> out-proj.

#define DM   768
#define SEQ  2048
#define NB   2
#define NH   12
#define DK   64
#define MROWS (NB*SEQ)                       // 4096
#define QSCALE 0.18033688011112042f          // (1/sqrt(64)) * log2(e): softmax in exp2 domain

typedef unsigned short u16;
typedef __bf16 bf16x8 __attribute__((ext_vector_type(8)));
typedef float  f32x4  __attribute__((ext_vector_type(4)));
typedef float  f32x16 __attribute__((ext_vector_type(16)));
typedef unsigned int u32x4 __attribute__((ext_vector_type(4)));

__device__ __forceinline__ u16 f2bf(float f) {      // RNE f32 -> bf16
  unsigned u = __builtin_bit_cast(unsigned, f);
  u += 0x7fffu + ((u >> 16) & 1u);
  return (u16)(u >> 16);
}

__device__ __forceinline__ unsigned cvtpk(float lo, float hi) {  // 2xbf16 pack, RNE
  unsigned r;
  asm("v_cvt_pk_bf16_f32 %0, %1, %2" : "=v"(r) : "v"(lo), "v"(hi));
  return r;
}

__device__ __forceinline__ bf16x8 ldbf8(const u16* p) {   // 16B aligned load
  return __builtin_bit_cast(bf16x8, *(const u32x4*)p);
}

__device__ __forceinline__ void gl_lds16(const void* g, void* l) {
  __builtin_amdgcn_global_load_lds((__attribute__((address_space(1))) void*)g,
                                   (__attribute__((address_space(3))) void*)l,
                                   16, 0, 0);
}

// ---------------- fp32 -> bf16 converts ----------------
__global__ void cvt_bf16(const float* __restrict__ s, u16* __restrict__ d, int n4) {
  int i = blockIdx.x * blockDim.x + threadIdx.x;
  if (i < n4) {
    const float4 v = ((const float4*)s)[i];
    ushort4 r;
    r.x = f2bf(v.x); r.y = f2bf(v.y); r.z = f2bf(v.z); r.w = f2bf(v.w);
    ((ushort4*)d)[i] = r;
  }
}

__global__ void cvt_w4(const float* __restrict__ s0, const float* __restrict__ s1,
                       const float* __restrict__ s2, const float* __restrict__ s3,
                       u16* __restrict__ d, int n4) {
  const int i = blockIdx.x * blockDim.x + threadIdx.x;
  const int m = i / n4, r = i - m * n4;
  const float* s = (m == 0) ? s0 : (m == 1) ? s1 : (m == 2) ? s2 : s3;
  const float4 v = ((const float4*)s)[r];
  ushort4 rr;
  rr.x = f2bf(v.x); rr.y = f2bf(v.y); rr.z = f2bf(v.z); rr.w = f2bf(v.w);
  ((ushort4*)d)[i] = rr;
}

// ---------------- gemm_bt: C[m][n] = sum_k A[m][k]*B[n][k] (R9, kept) -------
template <int EPI, int TM>
__global__ __launch_bounds__(256, 3) void gemm_bt(
    const u16* __restrict__ A,
    const u16* __restrict__ B0, const u16* __restrict__ B1, const u16* __restrict__ B2,
    const float* __restrict__ bias0, const float* __restrict__ bias1, const float* __restrict__ bias2,
    u16* __restrict__ q_out, u16* __restrict__ k_out, u16* __restrict__ vt_out,
    float* __restrict__ f_out)
{
  constexpr int MF = TM / 32;
  __shared__ u16 At[3][TM*32];
  __shared__ u16 Bt[3][128*32];
  const int tid = threadIdx.x;
  const int w = tid >> 6, lane = tid & 63;
  const int lg = lane >> 4, ll = lane & 15;

  const int L = blockIdx.x;
  const int xcd = L & 7, li = L >> 3;
  int bm, bn;
  if (EPI == 0) { bm = xcd*4 + li/18; bn = li%18; }
  else          { bm = xcd*8 + li/6;  bn = li%6;  }
  const int row0 = bm * TM;

  const u16* Bm; const float* bias; int col0; int mat = 0;
  if (EPI == 0) {
    mat  = bn / 6;
    Bm   = (mat == 0) ? B0 : (mat == 1) ? B1 : B2;
    bias = (mat == 0) ? bias0 : (mat == 1) ? bias1 : bias2;
    col0 = (bn % 6) * 128;
  } else {
    Bm = B0; bias = bias0; col0 = bn * 128;
  }
  const int wr = w >> 1, wc = w & 1;

  f32x4 acc[MF][4] = {};

#define GSTAGE(BUF, K0) do {                                                  \
    _Pragma("unroll")                                                         \
    for (int c = w; c < TM/16; c += 4) {                                      \
      const int a = c*1024 + lane*16;                                         \
      gl_lds16((const char*)A + ((size_t)(row0 + (a>>6))*DM + (K0))*2 + (a&63), \
               (char*)At[BUF] + c*1024);                                      \
    }                                                                         \
    _Pragma("unroll")                                                         \
    for (int c = w; c < 8; c += 4) {                                          \
      const int a = c*1024 + lane*16;                                         \
      gl_lds16((const char*)Bm + ((size_t)(col0 + (a>>6))*DM + (K0))*2 + (a&63), \
               (char*)Bt[BUF] + c*1024);                                      \
    }                                                                         \
  } while (0)

  GSTAGE(0, 0);
  GSTAGE(1, 32);
  int cur = 0;
  const int nsteps = DM / 32;
#pragma unroll 1
  for (int j = 0; j < nsteps; ++j) {
    if (j + 1 < nsteps) {
      if constexpr (TM == 128) asm volatile("s_waitcnt vmcnt(4)" ::: "memory");
      else                     asm volatile("s_waitcnt vmcnt(3)" ::: "memory");
    } else {
      asm volatile("s_waitcnt vmcnt(0)" ::: "memory");
    }
    __builtin_amdgcn_s_barrier();
    __builtin_amdgcn_sched_barrier(0);
    if (j + 2 < nsteps) {
      int nb = cur + 2; if (nb >= 3) nb -= 3;
      GSTAGE(nb, (j + 2) * 32);
    }

    bf16x8 fa[MF], fb[4];
#pragma unroll
    for (int m = 0; m < MF; ++m)
      fa[m] = ldbf8(&At[cur][(wr*(TM/2) + m*16 + ll)*32 + lg*8]);
#pragma unroll
    for (int n = 0; n < 4; ++n)
      fb[n] = ldbf8(&Bt[cur][(wc*64 + n*16 + ll)*32 + lg*8]);
#pragma unroll
    for (int m = 0; m < MF; ++m)
#pragma unroll
      for (int n = 0; n < 4; ++n)
        acc[m][n] = __builtin_amdgcn_mfma_f32_16x16x32_bf16(fa[m], fb[n], acc[m][n], 0, 0, 0);
    cur = (cur == 2) ? 0 : cur + 1;
  }
#undef GSTAGE

#pragma unroll
  for (int m = 0; m < MF; ++m) {
#pragma unroll
    for (int n = 0; n < 4; ++n) {
      const int gn  = col0 + wc*64 + n*16 + ll;
      const float bv = bias[gn];
      const int gm0 = row0 + wr*(TM/2) + m*16 + lg*4;
#pragma unroll
      for (int j = 0; j < 4; ++j) {
        const float v = acc[m][n][j] + bv;
        const int gm = gm0 + j;
        if (EPI == 0) {
          const int b = gm >> 11, s = gm & 2047;
          const int h = gn >> 6,  d = gn & 63;
          const size_t bh = (size_t)(b*NH + h);
          if (mat == 0)      q_out[(bh*SEQ + s)*DK + d] = f2bf(v * QSCALE);
          else if (mat == 1) k_out[(bh*SEQ + s)*DK + d] = f2bf(v);
          else               vt_out[(bh*DK + d)*SEQ + s] = f2bf(v);
        } else {
          f_out[(size_t)gm*DM + gn] = v;
        }
      }
    }
  }
}

// ---------------- flash attention v12: 8-wave 256-q blocks, 32x32 MFMA ------
// grid 192 = 8 XCD x 3 bh x 8 q-blocks (xcd=L&7 -> KV L2-resident per XCD).
// Block = 512 thr = 8 waves; wave w owns q-rows [qb0+32w, +32). One shared KV
// stream: tile t = K[64 kv][64 d] + V^T[64 d][64 s] staged into 3 LDS buffers
// by ALL waves (2 gl_lds each), consumed by all -> staging/DS amortized 8x.
// Pipeline: counted vmcnt(2) + 1 barrier/tile; stage(t+2) post-barrier into
// buf[(t+2)%3] whose readers (iter t-1) passed this barrier.
// QK^T swapped, 32x32x16: st[s] lane(c=lane&31,hi=lane>>5) = S^T[kv=32s+
// (r&3)+8(r>>2)+4hi][q=wq0+c]. Softmax in-register (defer-max thr=8; l as
// per-lane partial, pair-combined at end via shfl_xor 32). P -> PV B-operand
// entirely in-register: 16 cvt_pk + 8 v_permlane32_swap (word pairs
// (w0,w2)=swap(pw[b],pw[b+2]), (w1,w3)=swap(pw[b+1],pw[b+3]), b=(ck&1)*4,
// subtile s=ck>>1). PV: O^T[d][q] += mfma(A=V^T frag, B=P frag), 2 d-tiles x
// 4 kv-chunks. Causal: wave computes t < my_nt only (idles through barriers
// after); mask on t==my_nt-1. No cross-wave merge needed.

__device__ __forceinline__ bf16x8 ldT(const u16* T, int row, int bo) {
  // swizzled 16B read at logical (row, byte bo) of a [64][128B] LDS tile
  return ldbf8((const u16*)((const char*)T + row*128 + (bo ^ ((row & 7) << 4))));
}

__global__ __launch_bounds__(512, 1) void attn_fwd(
    const u16* __restrict__ qb, const u16* __restrict__ kb,
    const u16* __restrict__ vtb, u16* __restrict__ attb)
{
  __shared__ u16 KV[3][2][64*64];               // [buf][K|V] = 48KB
  const int L = blockIdx.x;
  const int xcd = L & 7, li = L >> 3;            // li 0..23
  const int bh = xcd*3 + (li % 3);
  const int qblk = li / 3;                       // 0..7
  const int tid = threadIdx.x;
  const int w = tid >> 6, lane = tid & 63;
  const int c = lane & 31, hi = lane >> 5;
  const u16* qp = qb  + (size_t)bh * SEQ * DK;
  const u16* kp = kb  + (size_t)bh * SEQ * DK;
  const u16* vp = vtb + (size_t)bh * DK * SEQ;
  const int bb = bh / NH, hh = bh % NH;

  const int qb0 = qblk * 256;
  const int wq0 = qb0 + w * 32;
  const int nt_blk = qb0/64 + 4;                 // tiles staged by the block
  const int my_nt  = wq0/64 + 1;                 // tiles this wave computes

  // Q B-operand frags: lane holds Q[q=wq0+c][d = dck*16 + hi*8 + 0..7]
  bf16x8 qf[4];
#pragma unroll
  for (int dck = 0; dck < 4; ++dck)
    qf[dck] = ldbf8(&qp[(size_t)(wq0 + c)*DK + dck*16 + hi*8]);

  f32x16 o[2] = {};                              // O^T d-subtiles (dt=0,1)
  float mrun = 0.f, lrun = 0.f;                  // defer-thr bounds P<=2^8

  // stage tile T into buffer BUF: wave w covers chunks w*128+i*64+lane
#define STAGE(T, BUF) do {                                                    \
    const char* kg_ = (const char*)kp + (size_t)(T) * 64 * 128;               \
    const char* vg_ = (const char*)vp + (size_t)(T) * 128;                    \
    _Pragma("unroll")                                                         \
    for (int i2 = 0; i2 < 2; ++i2) {                                          \
      if (w < 4) {                                                            \
        const int ch = w*128 + i2*64 + lane;                                  \
        const int row = ch >> 3, cs = (ch & 7) ^ (row & 7);                   \
        gl_lds16(kg_ + row*128 + cs*16, (char*)KV[BUF][0] + w*2048 + i2*1024);\
      } else {                                                                \
        const int ch = (w-4)*128 + i2*64 + lane;                              \
        const int row = ch >> 3, cs = (ch & 7) ^ (row & 7);                   \
        gl_lds16(vg_ + (size_t)row*4096 + cs*16,                              \
                 (char*)KV[BUF][1] + (w-4)*2048 + i2*1024);                   \
      }                                                                       \
    }                                                                         \
  } while (0)

  STAGE(0, 0);
  STAGE(1, 1);

#pragma unroll 1
  for (int t = 0; t < nt_blk; ++t) {
    if (t + 1 < nt_blk) asm volatile("s_waitcnt vmcnt(2)" ::: "memory");
    else                asm volatile("s_waitcnt vmcnt(0)" ::: "memory");
    __builtin_amdgcn_s_barrier();                // all waves' stage(t) landed
    __builtin_amdgcn_sched_barrier(0);
    if (t + 2 < nt_blk) {
      const int nb = (t + 2) % 3;
      STAGE(t + 2, nb);
    }

    if (t < my_nt) {
      const u16* Kc = KV[t % 3][0];
      const u16* Vc = KV[t % 3][1];

      // QK: S^T = K . Q^T, 2 kv-subtiles, d chained 4x16
      f32x16 st[2] = {};
#pragma unroll
      for (int s2 = 0; s2 < 2; ++s2)
#pragma unroll
        for (int dck = 0; dck < 4; ++dck) {
          const bf16x8 kf = ldT(Kc, s2*32 + c, dck*32 + hi*16);
          st[s2] = __builtin_amdgcn_mfma_f32_32x32x16_bf16(kf, qf[dck], st[s2], 0, 0, 0);
        }

      if (t == my_nt - 1) {                      // diagonal tile: causal mask
#pragma unroll
        for (int s2 = 0; s2 < 2; ++s2)
#pragma unroll
          for (int r2 = 0; r2 < 16; ++r2) {
            const int kv = t*64 + s2*32 + (r2 & 3) + 8*(r2 >> 2) + 4*hi;
            if (kv > wq0 + c) st[s2][r2] = -1e30f;
          }
      }

      // defer-max: per-lane local max over own 32 scores
      float lm = -1e30f;
#pragma unroll
      for (int s2 = 0; s2 < 2; ++s2)
#pragma unroll
        for (int r2 = 0; r2 < 16; ++r2)
          lm = fmaxf(lm, st[s2][r2]);

      if (!__all(lm <= mrun + 8.f)) {            // rare: rescale
        const float mt = fmaxf(lm, __shfl_xor(lm, 32));
        const float mn = fmaxf(mrun, mt);
        const float sc = exp2f(mrun - mn);
        lrun *= sc;
        o[0] *= sc;
        o[1] *= sc;
        mrun = mn;
      }

      // P = exp2(S - m), packed to bf16 pairs (pw[s*8+r2] = kv pair 2r2,2r2+1)
      float psum = 0.f;
      unsigned pw[16];
#pragma unroll
      for (int s2 = 0; s2 < 2; ++s2)
#pragma unroll
        for (int r2 = 0; r2 < 8; ++r2) {
          const float e0 = exp2f(st[s2][2*r2]   - mrun);
          const float e1 = exp2f(st[s2][2*r2+1] - mrun);
          psum += e0 + e1;
          pw[s2*8 + r2] = cvtpk(e0, e1);
        }
      lrun += psum;

      // build PV B-frags in-register: lane(c,hi) needs P^T[kv=16ck+8hi+j][q=c]
      bf16x8 pbf[4];
#pragma unroll
      for (int ck = 0; ck < 4; ++ck) {
        const int base = (ck >> 1)*8 + (ck & 1)*4;
        unsigned x0 = pw[base + 0], y0 = pw[base + 2];
        unsigned x1 = pw[base + 1], y1 = pw[base + 3];
        asm volatile("v_permlane32_swap_b32 %0, %1" : "+v"(x0), "+v"(y0));
        asm volatile("v_permlane32_swap_b32 %0, %1" : "+v"(x1), "+v"(y1));
        const u32x4 pk = {x0, x1, y0, y1};       // words j(0,1),(2,3),(4,5),(6,7)
        pbf[ck] = __builtin_bit_cast(bf16x8, pk);
      }

      // PV: O^T[d][q] += V^T . P^T, 2 d-subtiles, kv chained 4x16
#pragma unroll
      for (int dt = 0; dt < 2; ++dt)
#pragma unroll
        for (int ck = 0; ck < 4; ++ck) {
          const bf16x8 vf = ldT(Vc, dt*32 + c, ck*32 + hi*16);
          o[dt] = __builtin_amdgcn_mfma_f32_32x32x16_bf16(vf, pbf[ck], o[dt], 0, 0, 0);
        }
    }
  }
#undef STAGE

  // epilogue: combine l across the hi pair (full q-row), scale, store
  const float lt = lrun + __shfl_xor(lrun, 32);
  const float li2 = 1.0f / lt;
  u16* orow = &attb[(size_t)(bb*SEQ + wq0 + c)*DM + hh*64];
#pragma unroll
  for (int dt = 0; dt < 2; ++dt)
#pragma unroll
    for (int g = 0; g < 4; ++g) {
      const int d0 = dt*32 + g*8 + hi*4;         // rows (r&3)+8g+4hi, 4 consecutive
      const unsigned a  = cvtpk(o[dt][4*g+0]*li2, o[dt][4*g+1]*li2);
      const unsigned b2 = cvtpk(o[dt][4*g+2]*li2, o[dt][4*g+3]*li2);
      *(uint2*)&orow[d0] = make_uint2(a, b2);
    }
}

// ---------------- launch ----------------
extern "C" void kernel_launch(void* const* d_in, const int* in_sizes, int n_in,
                              void* d_out, int out_size, void* d_ws, size_t ws_size,
                              hipStream_t stream) {
  const float* x  = (const float*)d_in[0];
  const float* wq = (const float*)d_in[1];
  const float* bq = (const float*)d_in[2];
  const float* wk = (const float*)d_in[3];
  const float* bk = (const float*)d_in[4];
  const float* wv = (const float*)d_in[5];
  const float* bv = (const float*)d_in[6];
  const float* wo = (const float*)d_in[7];
  const float* bo = (const float*)d_in[8];
  float* out = (float*)d_out;

  char* ws = (char*)d_ws;
  u16* xb   = (u16*)(ws);               // [4096][768]
  u16* wqb  = (u16*)(ws + 6291456);     // [768][768] x4 contiguous
  u16* wkb  = (u16*)(ws + 7471104);
  u16* wvb  = (u16*)(ws + 8650752);
  u16* wob  = (u16*)(ws + 9830400);
  u16* qb   = (u16*)(ws + 11010048);    // [24][2048][64] scaled
  u16* kb   = (u16*)(ws + 17301504);    // [24][2048][64]
  u16* vtb  = (u16*)(ws + 23592960);    // [24][64][2048]
  u16* attb = (u16*)(ws + 29884416);    // [4096][768]

  const int nx4 = MROWS*DM/4;
  const int nw4 = DM*DM/4;
  cvt_bf16<<<(nx4+255)/256, 256, 0, stream>>>(x, xb, nx4);
  cvt_w4<<<(4*nw4)/256, 256, 0, stream>>>(wq, wk, wv, wo, wqb, nw4);

  gemm_bt<0,128><<<576, 256, 0, stream>>>(xb, wqb, wkb, wvb, bq, bk, bv,
                                          qb, kb, vtb, nullptr);
  attn_fwd<<<192, 512, 0, stream>>>(qb, kb, vtb, attb);
  gemm_bt<1,64><<<384, 256, 0, stream>>>(attb, wob, nullptr, nullptr, bo, nullptr, nullptr,
                                         nullptr, nullptr, nullptr, out);
}

// Round 13
// 108.256 us; speedup vs baseline: 1.1774x; 1.1774x over previous
//
#include <hip/hip_runtime.h>

// MHA forward, MI355X gfx950. bf16 MFMA pipeline, fp32 accumulate.
// Consolidation: merged cvt -> R9 gemm_bt (XCD-decoded, 2-deep pipeline)
//                -> R8 flash attention (parity split-KV, LDS staging, best
//                   measured: 51.5us) -> R9 out-proj gemm_bt (64x128).

#define DM   768
#define SEQ  2048
#define NB   2
#define NH   12
#define DK   64
#define MROWS (NB*SEQ)                       // 4096
#define QSCALE 0.18033688011112042f          // (1/sqrt(64)) * log2(e): softmax in exp2 domain

typedef unsigned short u16;
typedef __bf16 bf16x8 __attribute__((ext_vector_type(8)));
typedef float  f32x4  __attribute__((ext_vector_type(4)));
typedef unsigned int u32x4 __attribute__((ext_vector_type(4)));

__device__ __forceinline__ u16 f2bf(float f) {      // RNE f32 -> bf16
  unsigned u = __builtin_bit_cast(unsigned, f);
  u += 0x7fffu + ((u >> 16) & 1u);
  return (u16)(u >> 16);
}

__device__ __forceinline__ unsigned cvtpk(float lo, float hi) {  // 2xbf16 pack, RNE
  unsigned r;
  asm("v_cvt_pk_bf16_f32 %0, %1, %2" : "=v"(r) : "v"(lo), "v"(hi));
  return r;
}

__device__ __forceinline__ bf16x8 ldbf8(const u16* p) {   // 16B aligned load
  return __builtin_bit_cast(bf16x8, *(const u32x4*)p);
}

__device__ __forceinline__ void gl_lds16(const void* g, void* l) {
  __builtin_amdgcn_global_load_lds((__attribute__((address_space(1))) void*)g,
                                   (__attribute__((address_space(3))) void*)l,
                                   16, 0, 0);
}

// ---------------- fp32 -> bf16 convert, single launch (x + 4 weights) -------
__global__ void cvt_all(const float* __restrict__ x,
                        const float* __restrict__ w0, const float* __restrict__ w1,
                        const float* __restrict__ w2, const float* __restrict__ w3,
                        u16* __restrict__ dx, u16* __restrict__ dw,
                        int nx4, int nw4) {
  const int i = blockIdx.x * blockDim.x + threadIdx.x;
  const float* s; ushort4* d; int idx;
  if (i < nx4) {
    s = x; d = (ushort4*)dx; idx = i;
  } else {
    const int j = i - nx4;
    const int m = j / nw4;
    idx = j - m * nw4;
    s = (m == 0) ? w0 : (m == 1) ? w1 : (m == 2) ? w2 : w3;
    d = (ushort4*)dw + (size_t)m * nw4;
  }
  const float4 v = ((const float4*)s)[idx];
  ushort4 rr;
  rr.x = f2bf(v.x); rr.y = f2bf(v.y); rr.z = f2bf(v.z); rr.w = f2bf(v.w);
  d[idx] = rr;
}

// ---------------- gemm_bt: C[m][n] = sum_k A[m][k]*B[n][k] (R9) -------------
// TM x 128 tile, 2-deep pipelined (3 LDS buffer sets, counted vmcnt), linear
// grid with XCD-clustered decode. EPI0: TM=128, grid 576 (8 xcd x 4 bm x 18
// bn) -> 3 blocks/CU single round. EPI1: TM=64, grid 384 (8 x 8 bm x 6 bn).
template <int EPI, int TM>
__global__ __launch_bounds__(256, 3) void gemm_bt(
    const u16* __restrict__ A,
    const u16* __restrict__ B0, const u16* __restrict__ B1, const u16* __restrict__ B2,
    const float* __restrict__ bias0, const float* __restrict__ bias1, const float* __restrict__ bias2,
    u16* __restrict__ q_out, u16* __restrict__ k_out, u16* __restrict__ vt_out,
    float* __restrict__ f_out)
{
  constexpr int MF = TM / 32;
  __shared__ u16 At[3][TM*32];
  __shared__ u16 Bt[3][128*32];
  const int tid = threadIdx.x;
  const int w = tid >> 6, lane = tid & 63;
  const int lg = lane >> 4, ll = lane & 15;

  const int L = blockIdx.x;
  const int xcd = L & 7, li = L >> 3;
  int bm, bn;
  if (EPI == 0) { bm = xcd*4 + li/18; bn = li%18; }
  else          { bm = xcd*8 + li/6;  bn = li%6;  }
  const int row0 = bm * TM;

  const u16* Bm; const float* bias; int col0; int mat = 0;
  if (EPI == 0) {
    mat  = bn / 6;
    Bm   = (mat == 0) ? B0 : (mat == 1) ? B1 : B2;
    bias = (mat == 0) ? bias0 : (mat == 1) ? bias1 : bias2;
    col0 = (bn % 6) * 128;
  } else {
    Bm = B0; bias = bias0; col0 = bn * 128;
  }
  const int wr = w >> 1, wc = w & 1;

  f32x4 acc[MF][4] = {};

#define GSTAGE(BUF, K0) do {                                                  \
    _Pragma("unroll")                                                         \
    for (int c = w; c < TM/16; c += 4) {                                      \
      const int a = c*1024 + lane*16;                                         \
      gl_lds16((const char*)A + ((size_t)(row0 + (a>>6))*DM + (K0))*2 + (a&63), \
               (char*)At[BUF] + c*1024);                                      \
    }                                                                         \
    _Pragma("unroll")                                                         \
    for (int c = w; c < 8; c += 4) {                                          \
      const int a = c*1024 + lane*16;                                         \
      gl_lds16((const char*)Bm + ((size_t)(col0 + (a>>6))*DM + (K0))*2 + (a&63), \
               (char*)Bt[BUF] + c*1024);                                      \
    }                                                                         \
  } while (0)

  GSTAGE(0, 0);
  GSTAGE(1, 32);
  int cur = 0;
  const int nsteps = DM / 32;
#pragma unroll 1
  for (int j = 0; j < nsteps; ++j) {
    if (j + 1 < nsteps) {
      if constexpr (TM == 128) asm volatile("s_waitcnt vmcnt(4)" ::: "memory");
      else                     asm volatile("s_waitcnt vmcnt(3)" ::: "memory");
    } else {
      asm volatile("s_waitcnt vmcnt(0)" ::: "memory");
    }
    __builtin_amdgcn_s_barrier();
    __builtin_amdgcn_sched_barrier(0);
    if (j + 2 < nsteps) {
      int nb = cur + 2; if (nb >= 3) nb -= 3;
      GSTAGE(nb, (j + 2) * 32);
    }

    bf16x8 fa[MF], fb[4];
#pragma unroll
    for (int m = 0; m < MF; ++m)
      fa[m] = ldbf8(&At[cur][(wr*(TM/2) + m*16 + ll)*32 + lg*8]);
#pragma unroll
    for (int n = 0; n < 4; ++n)
      fb[n] = ldbf8(&Bt[cur][(wc*64 + n*16 + ll)*32 + lg*8]);
#pragma unroll
    for (int m = 0; m < MF; ++m)
#pragma unroll
      for (int n = 0; n < 4; ++n)
        acc[m][n] = __builtin_amdgcn_mfma_f32_16x16x32_bf16(fa[m], fb[n], acc[m][n], 0, 0, 0);
    cur = (cur == 2) ? 0 : cur + 1;
  }
#undef GSTAGE

#pragma unroll
  for (int m = 0; m < MF; ++m) {
#pragma unroll
    for (int n = 0; n < 4; ++n) {
      const int gn  = col0 + wc*64 + n*16 + ll;
      const float bv = bias[gn];
      const int gm0 = row0 + wr*(TM/2) + m*16 + lg*4;
#pragma unroll
      for (int j = 0; j < 4; ++j) {
        const float v = acc[m][n][j] + bv;
        const int gm = gm0 + j;
        if (EPI == 0) {
          const int b = gm >> 11, s = gm & 2047;
          const int h = gn >> 6,  d = gn & 63;
          const size_t bh = (size_t)(b*NH + h);
          if (mat == 0)      q_out[(bh*SEQ + s)*DK + d] = f2bf(v * QSCALE);
          else if (mat == 1) k_out[(bh*SEQ + s)*DK + d] = f2bf(v);
          else               vt_out[(bh*DK + d)*SEQ + s] = f2bf(v);
        } else {
          f_out[(size_t)gm*DM + gn] = v;
        }
      }
    }
  }
}

// ---------------- flash attention (R8, best measured 51.5us) ----------------
// grid 768 linear, XCD-clustered (xcd=L&7, bh=xcd*3+(rr0%3), pairb=rr0/3).
// Block = 256 thr = 4 waves: r = w&1 row-chunk (16 rows), h = w>>1 KV parity.
// Parity pair h processes tiles t = h, h+2, ... of the current q-tile, with
// its OWN double-buffered LDS KV stream (async gl_lds - the only transport
// that works here, R5/R7 evidence). Two tiles consumed per barrier-iter ->
// wall-iters = ceil(ntA/2)+ceil(ntB/2) = 17..18, balanced. Halves {63-p, p}
// sequential. Parity partials merged per half through LDS arena (unioned
// with P-repack buffer). Swapped QK^T; defer-max (thr=8).

__device__ __forceinline__ void stage_kv(const u16* kp, const u16* vp, int kv0,
                                         u16* Kb, u16* Vb, int r, int lane) {
  const char* kg = (const char*)kp + (size_t)kv0 * 128;   // K rows contiguous
  const char* vg = (const char*)vp + (size_t)kv0 * 2;     // V^T rows stride 4096B
#pragma unroll
  for (int j = 0; j < 4; ++j) {
    const int base = (r*4 + j) * 1024;          // wave-uniform base; HW adds lane*16
    const int a = base + lane*16;
    const int row = a >> 7;                     // 128B rows
    const int cs  = ((a >> 4) & 7) ^ (row & 7); // inverse-swizzled source chunk
    gl_lds16(kg + row*128 + cs*16, (char*)Kb + base);
    gl_lds16(vg + (size_t)row*4096 + cs*16, (char*)Vb + base);
  }
}

__device__ __forceinline__ bf16x8 ldtile(const u16* T, int row, int wo) {
  // swizzled read of 16B at logical (row, byte-offset wo) from a [64][64] bf16 tile
  return ldbf8((const u16*)((const char*)T + row*128 + (wo ^ ((row & 7) << 4))));
}

__global__ __launch_bounds__(256, 2) void attn_fwd(
    const u16* __restrict__ qb, const u16* __restrict__ kb,
    const u16* __restrict__ vtb, u16* __restrict__ attb)
{
  __shared__ u16 KVb[2][2][2][64*64];           // [parity][dbuf][K|V] = 64KB
  __shared__ __align__(16) char arena[9216];    // P repack (loop) / merge (epilogue)
  const int L = blockIdx.x;
  const int xcd = L & 7, rr0 = L >> 3;
  const int bh = xcd * 3 + (rr0 % 3);            // XCD-clustered: 3 bh per XCD
  const int pairb = rr0 / 3;                     // 0..31
  const int tid = threadIdx.x;
  const int w = tid >> 6, lane = tid & 63;
  const int r = w & 1, h = w >> 1;               // row-chunk, KV-parity
  const int lg = lane >> 4, ll = lane & 15;
  const u16* qp = qb  + (size_t)bh * SEQ * DK;
  const u16* kp = kb  + (size_t)bh * SEQ * DK;
  const u16* vp = vtb + (size_t)bh * DK * SEQ;
  const int b = bh / NH, hh = bh % NH;
  u16* Pl = (u16*)(arena + w*2304);              // 16 rows x 72 u16 per wave
  float* mg = (float*)(arena + r*4608) + lane*18;

#pragma unroll 1
  for (int half = 0; half < 2; ++half) {
    const int tile = half ? pairb : 63 - pairb;  // 32-row q-tiles, balanced pair
    const int nt = (tile >> 1) + 1;              // KV tiles needed (causal)
    const int q0 = tile * 32 + r * 16;

    const bf16x8 qf0 = ldbf8(&qp[(size_t)(q0 + ll)*DK + lg*8]);
    const bf16x8 qf1 = ldbf8(&qp[(size_t)(q0 + ll)*DK + 32 + lg*8]);

    f32x4 o[4] = {};                             // lane holds O[q0+ll][dt*16+lg*4+j]
    float mrun = 0.f, lrun = 0.f;                // m=0 valid: defer-thr bounds P<=2^8

    const int nI = (nt + 1) >> 1;                // barrier-iters (= parity-0 tile count)
    if (h < nt) stage_kv(kp, vp, h*64, KVb[h][0][0], KVb[h][0][1], r, lane);

#pragma unroll 1
    for (int i = 0; i < nI; ++i) {
      const int t = h + 2*i;                     // this parity's tile
      if (t < nt) asm volatile("s_waitcnt vmcnt(0)" ::: "memory");
      __builtin_amdgcn_s_barrier();              // own + partner stage(t) landed
      __builtin_amdgcn_sched_barrier(0);
      if (t + 2 < nt)                            // stage own-next into other buf
        stage_kv(kp, vp, (t+2)*64, KVb[h][(i+1)&1][0], KVb[h][(i+1)&1][1], r, lane);

      if (t < nt) {
        const u16* Kc = KVb[h][i&1][0];
        const u16* Vc = KVb[h][i&1][1];

        // S^T = K . Q^T over d=64
        f32x4 st[4] = {};
        __builtin_amdgcn_s_setprio(1);
#pragma unroll
        for (int kt = 0; kt < 4; ++kt) {
          const int rr = kt*16 + ll;
          st[kt] = __builtin_amdgcn_mfma_f32_16x16x32_bf16(ldtile(Kc, rr, lg*16),      qf0, st[kt], 0,0,0);
          st[kt] = __builtin_amdgcn_mfma_f32_16x16x32_bf16(ldtile(Kc, rr, 64 + lg*16), qf1, st[kt], 0,0,0);
        }
        __builtin_amdgcn_s_setprio(0);
        if (t == nt - 1) {                       // diagonal tile: causal mask
          const int kvb = t*64;
#pragma unroll
          for (int kt = 0; kt < 4; ++kt)
#pragma unroll
            for (int j = 0; j < 4; ++j)
              if (kvb + kt*16 + lg*4 + j > q0 + ll) st[kt][j] = -1e30f;
        }

        float lm = -1e30f;
#pragma unroll
        for (int kt = 0; kt < 4; ++kt)
          lm = fmaxf(lm, fmaxf(fmaxf(st[kt][0], st[kt][1]), fmaxf(st[kt][2], st[kt][3])));

        if (!__all(lm <= mrun + 8.f)) {          // rare: real max growth -> rescale
          float mt = lm;
          mt = fmaxf(mt, __shfl_xor(mt, 16));
          mt = fmaxf(mt, __shfl_xor(mt, 32));
          const float mn = fmaxf(mrun, mt);
          const float sc = exp2f(mrun - mn);
          lrun *= sc;
#pragma unroll
          for (int dt = 0; dt < 4; ++dt)
#pragma unroll
            for (int j = 0; j < 4; ++j)
              o[dt][j] *= sc;
          mrun = mn;
        }

        float psum = 0.f;
        unsigned pd[8];
#pragma unroll
        for (int kt = 0; kt < 4; ++kt) {
          const float e0 = exp2f(st[kt][0] - mrun);
          const float e1 = exp2f(st[kt][1] - mrun);
          const float e2 = exp2f(st[kt][2] - mrun);
          const float e3 = exp2f(st[kt][3] - mrun);
          psum += (e0 + e1) + (e2 + e3);
          pd[kt*2]   = cvtpk(e0, e1);
          pd[kt*2+1] = cvtpk(e2, e3);
        }
        lrun += psum;                            // per-lane partial (own k-chunks)

        // P repack (same-wave LDS round-trip; DS in-order within wave)
#pragma unroll
        for (int kt = 0; kt < 4; ++kt)
          *(uint2*)&Pl[ll*72 + kt*16 + lg*4] = make_uint2(pd[kt*2], pd[kt*2+1]);
        const bf16x8 pb0 = ldbf8(&Pl[ll*72 + lg*8]);
        const bf16x8 pb1 = ldbf8(&Pl[ll*72 + 32 + lg*8]);

        // O^T += V^T . P^T
        __builtin_amdgcn_s_setprio(1);
#pragma unroll
        for (int dt = 0; dt < 4; ++dt) {
          const int rr = dt*16 + ll;
          o[dt] = __builtin_amdgcn_mfma_f32_16x16x32_bf16(ldtile(Vc, rr, lg*16),      pb0, o[dt], 0,0,0);
          o[dt] = __builtin_amdgcn_mfma_f32_16x16x32_bf16(ldtile(Vc, rr, 64 + lg*16), pb1, o[dt], 0,0,0);
        }
        __builtin_amdgcn_s_setprio(0);
      }
    }

    // per-parity row totals (row-uniform across the 4 lane-groups)
    float lt = lrun;
    lt += __shfl_xor(lt, 16);
    lt += __shfl_xor(lt, 32);

    // merge parity partials through arena: h=1 publishes, h=0 merges + stores
    __syncthreads();                             // all P-reads done; arena reusable
    if (h == 1) {
#pragma unroll
      for (int dt = 0; dt < 4; ++dt)
#pragma unroll
        for (int j = 0; j < 4; ++j)
          mg[dt*4 + j] = o[dt][j];
      mg[16] = mrun;
      mg[17] = lt;
    }
    __syncthreads();
    if (h == 0) {
      const float mB = mg[16], lB = mg[17];
      const float ms = fmaxf(mrun, mB);
      const float sA = exp2f(mrun - ms), sB = exp2f(mB - ms);
      const float li = 1.0f / (lt * sA + lB * sB);
      u16* orow = &attb[(size_t)(b*SEQ + q0 + ll)*DM + hh*64];
#pragma unroll
      for (int dt = 0; dt < 4; ++dt) {
        ushort4 rw;
        rw.x = f2bf((o[dt][0]*sA + mg[dt*4+0]*sB) * li);
        rw.y = f2bf((o[dt][1]*sA + mg[dt*4+1]*sB) * li);
        rw.z = f2bf((o[dt][2]*sA + mg[dt*4+2]*sB) * li);
        rw.w = f2bf((o[dt][3]*sA + mg[dt*4+3]*sB) * li);
        *(ushort4*)&orow[dt*16 + lg*4] = rw;
      }
    }
    __syncthreads();                             // arena free before next half
  }
}

// ---------------- launch ----------------
extern "C" void kernel_launch(void* const* d_in, const int* in_sizes, int n_in,
                              void* d_out, int out_size, void* d_ws, size_t ws_size,
                              hipStream_t stream) {
  const float* x  = (const float*)d_in[0];
  const float* wq = (const float*)d_in[1];
  const float* bq = (const float*)d_in[2];
  const float* wk = (const float*)d_in[3];
  const float* bk = (const float*)d_in[4];
  const float* wv = (const float*)d_in[5];
  const float* bv = (const float*)d_in[6];
  const float* wo = (const float*)d_in[7];
  const float* bo = (const float*)d_in[8];
  float* out = (float*)d_out;

  char* ws = (char*)d_ws;
  u16* xb   = (u16*)(ws);               // [4096][768]
  u16* wqb  = (u16*)(ws + 6291456);     // [768][768] x4 contiguous (wq,wk,wv,wo)
  u16* wkb  = (u16*)(ws + 7471104);
  u16* wvb  = (u16*)(ws + 8650752);
  u16* wob  = (u16*)(ws + 9830400);
  u16* qb   = (u16*)(ws + 11010048);    // [24][2048][64] scaled
  u16* kb   = (u16*)(ws + 17301504);    // [24][2048][64]
  u16* vtb  = (u16*)(ws + 23592960);    // [24][64][2048]
  u16* attb = (u16*)(ws + 29884416);    // [4096][768]

  const int nx4 = MROWS*DM/4;           // 786432
  const int nw4 = DM*DM/4;              // 147456
  const int ntot = nx4 + 4*nw4;         // 1376256 = 5376 * 256
  cvt_all<<<ntot/256, 256, 0, stream>>>(x, wq, wk, wv, wo, xb, wqb, nx4, nw4);

  gemm_bt<0,128><<<576, 256, 0, stream>>>(xb, wqb, wkb, wvb, bq, bk, bv,
                                          qb, kb, vtb, nullptr);
  attn_fwd<<<768, 256, 0, stream>>>(qb, kb, vtb, attb);
  gemm_bt<1,64><<<384, 256, 0, stream>>>(attb, wob, nullptr, nullptr, bo, nullptr, nullptr,
                                         nullptr, nullptr, nullptr, out);
}

// Round 14
// 101.216 us; speedup vs baseline: 1.2593x; 1.0696x over previous
//
#include <hip/hip_runtime.h>

// MHA forward, MI355X gfx950. bf16 MFMA pipeline, fp32 accumulate.
// R14: R13 with attention KV staging single-buffered (32KB) -> 41KB LDS ->
//      3 blocks/CU (12 waves). TLP hides the exposed stage latency that the
//      double buffer used to hide (and couldn't, at 2 blocks/CU).

#define DM   768
#define SEQ  2048
#define NB   2
#define NH   12
#define DK   64
#define MROWS (NB*SEQ)                       // 4096
#define QSCALE 0.18033688011112042f          // (1/sqrt(64)) * log2(e): softmax in exp2 domain

typedef unsigned short u16;
typedef __bf16 bf16x8 __attribute__((ext_vector_type(8)));
typedef float  f32x4  __attribute__((ext_vector_type(4)));
typedef unsigned int u32x4 __attribute__((ext_vector_type(4)));

__device__ __forceinline__ u16 f2bf(float f) {      // RNE f32 -> bf16
  unsigned u = __builtin_bit_cast(unsigned, f);
  u += 0x7fffu + ((u >> 16) & 1u);
  return (u16)(u >> 16);
}

__device__ __forceinline__ unsigned cvtpk(float lo, float hi) {  // 2xbf16 pack, RNE
  unsigned r;
  asm("v_cvt_pk_bf16_f32 %0, %1, %2" : "=v"(r) : "v"(lo), "v"(hi));
  return r;
}

__device__ __forceinline__ bf16x8 ldbf8(const u16* p) {   // 16B aligned load
  return __builtin_bit_cast(bf16x8, *(const u32x4*)p);
}

__device__ __forceinline__ void gl_lds16(const void* g, void* l) {
  __builtin_amdgcn_global_load_lds((__attribute__((address_space(1))) void*)g,
                                   (__attribute__((address_space(3))) void*)l,
                                   16, 0, 0);
}

// ---------------- fp32 -> bf16 convert, single launch (x + 4 weights) -------
__global__ void cvt_all(const float* __restrict__ x,
                        const float* __restrict__ w0, const float* __restrict__ w1,
                        const float* __restrict__ w2, const float* __restrict__ w3,
                        u16* __restrict__ dx, u16* __restrict__ dw,
                        int nx4, int nw4) {
  const int i = blockIdx.x * blockDim.x + threadIdx.x;
  const float* s; ushort4* d; int idx;
  if (i < nx4) {
    s = x; d = (ushort4*)dx; idx = i;
  } else {
    const int j = i - nx4;
    const int m = j / nw4;
    idx = j - m * nw4;
    s = (m == 0) ? w0 : (m == 1) ? w1 : (m == 2) ? w2 : w3;
    d = (ushort4*)dw + (size_t)m * nw4;
  }
  const float4 v = ((const float4*)s)[idx];
  ushort4 rr;
  rr.x = f2bf(v.x); rr.y = f2bf(v.y); rr.z = f2bf(v.z); rr.w = f2bf(v.w);
  d[idx] = rr;
}

// ---------------- gemm_bt: C[m][n] = sum_k A[m][k]*B[n][k] (R9) -------------
template <int EPI, int TM>
__global__ __launch_bounds__(256, 3) void gemm_bt(
    const u16* __restrict__ A,
    const u16* __restrict__ B0, const u16* __restrict__ B1, const u16* __restrict__ B2,
    const float* __restrict__ bias0, const float* __restrict__ bias1, const float* __restrict__ bias2,
    u16* __restrict__ q_out, u16* __restrict__ k_out, u16* __restrict__ vt_out,
    float* __restrict__ f_out)
{
  constexpr int MF = TM / 32;
  __shared__ u16 At[3][TM*32];
  __shared__ u16 Bt[3][128*32];
  const int tid = threadIdx.x;
  const int w = tid >> 6, lane = tid & 63;
  const int lg = lane >> 4, ll = lane & 15;

  const int L = blockIdx.x;
  const int xcd = L & 7, li = L >> 3;
  int bm, bn;
  if (EPI == 0) { bm = xcd*4 + li/18; bn = li%18; }
  else          { bm = xcd*8 + li/6;  bn = li%6;  }
  const int row0 = bm * TM;

  const u16* Bm; const float* bias; int col0; int mat = 0;
  if (EPI == 0) {
    mat  = bn / 6;
    Bm   = (mat == 0) ? B0 : (mat == 1) ? B1 : B2;
    bias = (mat == 0) ? bias0 : (mat == 1) ? bias1 : bias2;
    col0 = (bn % 6) * 128;
  } else {
    Bm = B0; bias = bias0; col0 = bn * 128;
  }
  const int wr = w >> 1, wc = w & 1;

  f32x4 acc[MF][4] = {};

#define GSTAGE(BUF, K0) do {                                                  \
    _Pragma("unroll")                                                         \
    for (int c = w; c < TM/16; c += 4) {                                      \
      const int a = c*1024 + lane*16;                                         \
      gl_lds16((const char*)A + ((size_t)(row0 + (a>>6))*DM + (K0))*2 + (a&63), \
               (char*)At[BUF] + c*1024);                                      \
    }                                                                         \
    _Pragma("unroll")                                                         \
    for (int c = w; c < 8; c += 4) {                                          \
      const int a = c*1024 + lane*16;                                         \
      gl_lds16((const char*)Bm + ((size_t)(col0 + (a>>6))*DM + (K0))*2 + (a&63), \
               (char*)Bt[BUF] + c*1024);                                      \
    }                                                                         \
  } while (0)

  GSTAGE(0, 0);
  GSTAGE(1, 32);
  int cur = 0;
  const int nsteps = DM / 32;
#pragma unroll 1
  for (int j = 0; j < nsteps; ++j) {
    if (j + 1 < nsteps) {
      if constexpr (TM == 128) asm volatile("s_waitcnt vmcnt(4)" ::: "memory");
      else                     asm volatile("s_waitcnt vmcnt(3)" ::: "memory");
    } else {
      asm volatile("s_waitcnt vmcnt(0)" ::: "memory");
    }
    __builtin_amdgcn_s_barrier();
    __builtin_amdgcn_sched_barrier(0);
    if (j + 2 < nsteps) {
      int nb = cur + 2; if (nb >= 3) nb -= 3;
      GSTAGE(nb, (j + 2) * 32);
    }

    bf16x8 fa[MF], fb[4];
#pragma unroll
    for (int m = 0; m < MF; ++m)
      fa[m] = ldbf8(&At[cur][(wr*(TM/2) + m*16 + ll)*32 + lg*8]);
#pragma unroll
    for (int n = 0; n < 4; ++n)
      fb[n] = ldbf8(&Bt[cur][(wc*64 + n*16 + ll)*32 + lg*8]);
#pragma unroll
    for (int m = 0; m < MF; ++m)
#pragma unroll
      for (int n = 0; n < 4; ++n)
        acc[m][n] = __builtin_amdgcn_mfma_f32_16x16x32_bf16(fa[m], fb[n], acc[m][n], 0, 0, 0);
    cur = (cur == 2) ? 0 : cur + 1;
  }
#undef GSTAGE

#pragma unroll
  for (int m = 0; m < MF; ++m) {
#pragma unroll
    for (int n = 0; n < 4; ++n) {
      const int gn  = col0 + wc*64 + n*16 + ll;
      const float bv = bias[gn];
      const int gm0 = row0 + wr*(TM/2) + m*16 + lg*4;
#pragma unroll
      for (int j = 0; j < 4; ++j) {
        const float v = acc[m][n][j] + bv;
        const int gm = gm0 + j;
        if (EPI == 0) {
          const int b = gm >> 11, s = gm & 2047;
          const int h = gn >> 6,  d = gn & 63;
          const size_t bh = (size_t)(b*NH + h);
          if (mat == 0)      q_out[(bh*SEQ + s)*DK + d] = f2bf(v * QSCALE);
          else if (mat == 1) k_out[(bh*SEQ + s)*DK + d] = f2bf(v);
          else               vt_out[(bh*DK + d)*SEQ + s] = f2bf(v);
        } else {
          f_out[(size_t)gm*DM + gn] = v;
        }
      }
    }
  }
}

// ---------------- flash attention v14: single-buffered KV, 3 blocks/CU ------
// R8/R13 structure (parity split-KV, async gl_lds staging, balanced pairs,
// XCD clustering, swapped QK^T, defer-max) with SINGLE-buffered KV (32KB):
// per window: vmcnt(0)+barrier (stage landed) -> compute own tile ->
// barrier (all reads done) -> stage next own tile into same buffer.
// LDS 41KB -> 3 blocks/CU (12 waves): cross-block TLP hides the exposed
// stage latency that the double buffer couldn't hide at 2 blocks/CU.

__device__ __forceinline__ void stage_kv(const u16* kp, const u16* vp, int kv0,
                                         u16* Kb, u16* Vb, int r, int lane) {
  const char* kg = (const char*)kp + (size_t)kv0 * 128;   // K rows contiguous
  const char* vg = (const char*)vp + (size_t)kv0 * 2;     // V^T rows stride 4096B
#pragma unroll
  for (int j = 0; j < 4; ++j) {
    const int base = (r*4 + j) * 1024;          // wave-uniform base; HW adds lane*16
    const int a = base + lane*16;
    const int row = a >> 7;                     // 128B rows
    const int cs  = ((a >> 4) & 7) ^ (row & 7); // inverse-swizzled source chunk
    gl_lds16(kg + row*128 + cs*16, (char*)Kb + base);
    gl_lds16(vg + (size_t)row*4096 + cs*16, (char*)Vb + base);
  }
}

__device__ __forceinline__ bf16x8 ldtile(const u16* T, int row, int wo) {
  // swizzled read of 16B at logical (row, byte-offset wo) from a [64][64] bf16 tile
  return ldbf8((const u16*)((const char*)T + row*128 + (wo ^ ((row & 7) << 4))));
}

__global__ __launch_bounds__(256, 3) void attn_fwd(
    const u16* __restrict__ qb, const u16* __restrict__ kb,
    const u16* __restrict__ vtb, u16* __restrict__ attb)
{
  __shared__ u16 KVb[2][2][64*64];              // [parity][K|V] = 32KB (single buf)
  __shared__ __align__(16) char arena[9216];    // P repack (loop) / merge (epilogue)
  const int L = blockIdx.x;
  const int xcd = L & 7, rr0 = L >> 3;
  const int bh = xcd * 3 + (rr0 % 3);            // XCD-clustered: 3 bh per XCD
  const int pairb = rr0 / 3;                     // 0..31
  const int tid = threadIdx.x;
  const int w = tid >> 6, lane = tid & 63;
  const int r = w & 1, h = w >> 1;               // row-chunk, KV-parity
  const int lg = lane >> 4, ll = lane & 15;
  const u16* qp = qb  + (size_t)bh * SEQ * DK;
  const u16* kp = kb  + (size_t)bh * SEQ * DK;
  const u16* vp = vtb + (size_t)bh * DK * SEQ;
  const int b = bh / NH, hh = bh % NH;
  u16* Pl = (u16*)(arena + w*2304);              // 16 rows x 72 u16 per wave
  float* mg = (float*)(arena + r*4608) + lane*18;

#pragma unroll 1
  for (int half = 0; half < 2; ++half) {
    const int tile = half ? pairb : 63 - pairb;  // 32-row q-tiles, balanced pair
    const int nt = (tile >> 1) + 1;              // KV tiles needed (causal)
    const int q0 = tile * 32 + r * 16;

    const bf16x8 qf0 = ldbf8(&qp[(size_t)(q0 + ll)*DK + lg*8]);
    const bf16x8 qf1 = ldbf8(&qp[(size_t)(q0 + ll)*DK + 32 + lg*8]);

    f32x4 o[4] = {};                             // lane holds O[q0+ll][dt*16+lg*4+j]
    float mrun = 0.f, lrun = 0.f;                // m=0 valid: defer-thr bounds P<=2^8

    const int nI = (nt + 1) >> 1;                // windows (= parity-0 tile count)
    if (h < nt) stage_kv(kp, vp, h*64, KVb[h][0], KVb[h][1], r, lane);

#pragma unroll 1
    for (int i = 0; i < nI; ++i) {
      const int t = h + 2*i;                     // this parity's tile
      asm volatile("s_waitcnt vmcnt(0)" ::: "memory");   // own stage drained
      __builtin_amdgcn_s_barrier();              // all waves' stage landed
      __builtin_amdgcn_sched_barrier(0);

      if (t < nt) {
        const u16* Kc = KVb[h][0];
        const u16* Vc = KVb[h][1];

        // S^T = K . Q^T over d=64
        f32x4 st[4] = {};
        __builtin_amdgcn_s_setprio(1);
#pragma unroll
        for (int kt = 0; kt < 4; ++kt) {
          const int rr = kt*16 + ll;
          st[kt] = __builtin_amdgcn_mfma_f32_16x16x32_bf16(ldtile(Kc, rr, lg*16),      qf0, st[kt], 0,0,0);
          st[kt] = __builtin_amdgcn_mfma_f32_16x16x32_bf16(ldtile(Kc, rr, 64 + lg*16), qf1, st[kt], 0,0,0);
        }
        __builtin_amdgcn_s_setprio(0);
        if (t == nt - 1) {                       // diagonal tile: causal mask
          const int kvb = t*64;
#pragma unroll
          for (int kt = 0; kt < 4; ++kt)
#pragma unroll
            for (int j = 0; j < 4; ++j)
              if (kvb + kt*16 + lg*4 + j > q0 + ll) st[kt][j] = -1e30f;
        }

        float lm = -1e30f;
#pragma unroll
        for (int kt = 0; kt < 4; ++kt)
          lm = fmaxf(lm, fmaxf(fmaxf(st[kt][0], st[kt][1]), fmaxf(st[kt][2], st[kt][3])));

        if (!__all(lm <= mrun + 8.f)) {          // rare: real max growth -> rescale
          float mt = lm;
          mt = fmaxf(mt, __shfl_xor(mt, 16));
          mt = fmaxf(mt, __shfl_xor(mt, 32));
          const float mn = fmaxf(mrun, mt);
          const float sc = exp2f(mrun - mn);
          lrun *= sc;
#pragma unroll
          for (int dt = 0; dt < 4; ++dt)
#pragma unroll
            for (int j = 0; j < 4; ++j)
              o[dt][j] *= sc;
          mrun = mn;
        }

        float psum = 0.f;
        unsigned pd[8];
#pragma unroll
        for (int kt = 0; kt < 4; ++kt) {
          const float e0 = exp2f(st[kt][0] - mrun);
          const float e1 = exp2f(st[kt][1] - mrun);
          const float e2 = exp2f(st[kt][2] - mrun);
          const float e3 = exp2f(st[kt][3] - mrun);
          psum += (e0 + e1) + (e2 + e3);
          pd[kt*2]   = cvtpk(e0, e1);
          pd[kt*2+1] = cvtpk(e2, e3);
        }
        lrun += psum;                            // per-lane partial (own k-chunks)

        // P repack (same-wave LDS round-trip; DS in-order within wave)
#pragma unroll
        for (int kt = 0; kt < 4; ++kt)
          *(uint2*)&Pl[ll*72 + kt*16 + lg*4] = make_uint2(pd[kt*2], pd[kt*2+1]);
        const bf16x8 pb0 = ldbf8(&Pl[ll*72 + lg*8]);
        const bf16x8 pb1 = ldbf8(&Pl[ll*72 + 32 + lg*8]);

        // O^T += V^T . P^T
        __builtin_amdgcn_s_setprio(1);
#pragma unroll
        for (int dt = 0; dt < 4; ++dt) {
          const int rr = dt*16 + ll;
          o[dt] = __builtin_amdgcn_mfma_f32_16x16x32_bf16(ldtile(Vc, rr, lg*16),      pb0, o[dt], 0,0,0);
          o[dt] = __builtin_amdgcn_mfma_f32_16x16x32_bf16(ldtile(Vc, rr, 64 + lg*16), pb1, o[dt], 0,0,0);
        }
        __builtin_amdgcn_s_setprio(0);
      }

      __builtin_amdgcn_s_barrier();              // ALL waves' reads of KVb done
      if (t + 2 < nt)                            // restage same buffer for t+2
        stage_kv(kp, vp, (t+2)*64, KVb[h][0], KVb[h][1], r, lane);
    }

    // per-parity row totals (row-uniform across the 4 lane-groups)
    float lt = lrun;
    lt += __shfl_xor(lt, 16);
    lt += __shfl_xor(lt, 32);

    // merge parity partials through arena: h=1 publishes, h=0 merges + stores
    __syncthreads();                             // all P-reads done; arena reusable
    if (h == 1) {
#pragma unroll
      for (int dt = 0; dt < 4; ++dt)
#pragma unroll
        for (int j = 0; j < 4; ++j)
          mg[dt*4 + j] = o[dt][j];
      mg[16] = mrun;
      mg[17] = lt;
    }
    __syncthreads();
    if (h == 0) {
      const float mB = mg[16], lB = mg[17];
      const float ms = fmaxf(mrun, mB);
      const float sA = exp2f(mrun - ms), sB = exp2f(mB - ms);
      const float li = 1.0f / (lt * sA + lB * sB);
      u16* orow = &attb[(size_t)(b*SEQ + q0 + ll)*DM + hh*64];
#pragma unroll
      for (int dt = 0; dt < 4; ++dt) {
        ushort4 rw;
        rw.x = f2bf((o[dt][0]*sA + mg[dt*4+0]*sB) * li);
        rw.y = f2bf((o[dt][1]*sA + mg[dt*4+1]*sB) * li);
        rw.z = f2bf((o[dt][2]*sA + mg[dt*4+2]*sB) * li);
        rw.w = f2bf((o[dt][3]*sA + mg[dt*4+3]*sB) * li);
        *(ushort4*)&orow[dt*16 + lg*4] = rw;
      }
    }
    __syncthreads();                             // arena free before next half
  }
}

// ---------------- launch ----------------
extern "C" void kernel_launch(void* const* d_in, const int* in_sizes, int n_in,
                              void* d_out, int out_size, void* d_ws, size_t ws_size,
                              hipStream_t stream) {
  const float* x  = (const float*)d_in[0];
  const float* wq = (const float*)d_in[1];
  const float* bq = (const float*)d_in[2];
  const float* wk = (const float*)d_in[3];
  const float* bk = (const float*)d_in[4];
  const float* wv = (const float*)d_in[5];
  const float* bv = (const float*)d_in[6];
  const float* wo = (const float*)d_in[7];
  const float* bo = (const float*)d_in[8];
  float* out = (float*)d_out;

  char* ws = (char*)d_ws;
  u16* xb   = (u16*)(ws);               // [4096][768]
  u16* wqb  = (u16*)(ws + 6291456);     // [768][768] x4 contiguous (wq,wk,wv,wo)
  u16* wkb  = (u16*)(ws + 7471104);
  u16* wvb  = (u16*)(ws + 8650752);
  u16* wob  = (u16*)(ws + 9830400);
  u16* qb   = (u16*)(ws + 11010048);    // [24][2048][64] scaled
  u16* kb   = (u16*)(ws + 17301504);    // [24][2048][64]
  u16* vtb  = (u16*)(ws + 23592960);    // [24][64][2048]
  u16* attb = (u16*)(ws + 29884416);    // [4096][768]

  const int nx4 = MROWS*DM/4;           // 786432
  const int nw4 = DM*DM/4;              // 147456
  const int ntot = nx4 + 4*nw4;         // 1376256 = 5376 * 256
  cvt_all<<<ntot/256, 256, 0, stream>>>(x, wq, wk, wv, wo, xb, wqb, nx4, nw4);

  gemm_bt<0,128><<<576, 256, 0, stream>>>(xb, wqb, wkb, wvb, bq, bk, bv,
                                          qb, kb, vtb, nullptr);
  attn_fwd<<<768, 256, 0, stream>>>(qb, kb, vtb, attb);
  gemm_bt<1,64><<<384, 256, 0, stream>>>(attb, wob, nullptr, nullptr, bo, nullptr, nullptr,
                                         nullptr, nullptr, nullptr, out);
}

// Round 15
// 93.250 us; speedup vs baseline: 1.3668x; 1.0854x over previous
//
#include <hip/hip_runtime.h>

// MHA forward, MI355X gfx950. bf16 MFMA pipeline, fp32 accumulate.
// R15: R14 + grid-BALANCED GEMMs (TN=96): gemm0 32x24=768 blocks = exactly
//      3/CU (was 576 = 2.25/CU, wall set by 3-tile CUs); gemm1 64x8=512 = 2/CU
//      balanced (was 384 = 1.5/CU). Worst-CU work x0.75 each. Attn = R14.

#define DM   768
#define SEQ  2048
#define NB   2
#define NH   12
#define DK   64
#define MROWS (NB*SEQ)                       // 4096
#define QSCALE 0.18033688011112042f          // (1/sqrt(64)) * log2(e): softmax in exp2 domain

typedef unsigned short u16;
typedef __bf16 bf16x8 __attribute__((ext_vector_type(8)));
typedef float  f32x4  __attribute__((ext_vector_type(4)));
typedef unsigned int u32x4 __attribute__((ext_vector_type(4)));

__device__ __forceinline__ u16 f2bf(float f) {      // RNE f32 -> bf16
  unsigned u = __builtin_bit_cast(unsigned, f);
  u += 0x7fffu + ((u >> 16) & 1u);
  return (u16)(u >> 16);
}

__device__ __forceinline__ unsigned cvtpk(float lo, float hi) {  // 2xbf16 pack, RNE
  unsigned r;
  asm("v_cvt_pk_bf16_f32 %0, %1, %2" : "=v"(r) : "v"(lo), "v"(hi));
  return r;
}

__device__ __forceinline__ bf16x8 ldbf8(const u16* p) {   // 16B aligned load
  return __builtin_bit_cast(bf16x8, *(const u32x4*)p);
}

__device__ __forceinline__ void gl_lds16(const void* g, void* l) {
  __builtin_amdgcn_global_load_lds((__attribute__((address_space(1))) void*)g,
                                   (__attribute__((address_space(3))) void*)l,
                                   16, 0, 0);
}

// ---------------- fp32 -> bf16 convert, single launch (x + 4 weights) -------
__global__ void cvt_all(const float* __restrict__ x,
                        const float* __restrict__ w0, const float* __restrict__ w1,
                        const float* __restrict__ w2, const float* __restrict__ w3,
                        u16* __restrict__ dx, u16* __restrict__ dw,
                        int nx4, int nw4) {
  const int i = blockIdx.x * blockDim.x + threadIdx.x;
  const float* s; ushort4* d; int idx;
  if (i < nx4) {
    s = x; d = (ushort4*)dx; idx = i;
  } else {
    const int j = i - nx4;
    const int m = j / nw4;
    idx = j - m * nw4;
    s = (m == 0) ? w0 : (m == 1) ? w1 : (m == 2) ? w2 : w3;
    d = (ushort4*)dw + (size_t)m * nw4;
  }
  const float4 v = ((const float4*)s)[idx];
  ushort4 rr;
  rr.x = f2bf(v.x); rr.y = f2bf(v.y); rr.z = f2bf(v.z); rr.w = f2bf(v.w);
  d[idx] = rr;
}

// ---------------- gemm_bt: C[m][n] = sum_k A[m][k]*B[n][k] ------------------
// TM x 96 tiles, 2-deep pipelined (3 LDS buffer sets, counted vmcnt), linear
// grid, XCD-clustered decode, grid-balanced:
//   EPI0: TM=128, grid 768 (8 xcd x 4 bm x 24 bn) = exactly 3 blocks/CU.
//   EPI1: TM=64,  grid 512 (8 xcd x 8 bm x 8 bn)  = exactly 2 blocks/CU.
// Per-wave newest-stage loads (uneven B split 2/2/1/1): TM=128 -> 3, TM=64 -> 2.
template <int EPI, int TM>
__global__ __launch_bounds__(256, 3) void gemm_bt(
    const u16* __restrict__ A,
    const u16* __restrict__ B0, const u16* __restrict__ B1, const u16* __restrict__ B2,
    const float* __restrict__ bias0, const float* __restrict__ bias1, const float* __restrict__ bias2,
    u16* __restrict__ q_out, u16* __restrict__ k_out, u16* __restrict__ vt_out,
    float* __restrict__ f_out)
{
  constexpr int TN = 96;
  constexpr int MF = TM / 32;                   // acc frags in M per wave
  constexpr int NF = TN / 32;                   // acc frags in N per wave (3)
  __shared__ u16 At[3][TM*32];
  __shared__ u16 Bt[3][TN*32];
  const int tid = threadIdx.x;
  const int w = tid >> 6, lane = tid & 63;
  const int lg = lane >> 4, ll = lane & 15;

  const int L = blockIdx.x;
  const int xcd = L & 7, li = L >> 3;
  int bm, bn;
  if (EPI == 0) { bm = xcd*4 + li/24; bn = li%24; }    // 32 bm, 24 bn
  else          { bm = xcd*8 + li/8;  bn = li%8;  }    // 64 bm, 8 bn
  const int row0 = bm * TM;

  const u16* Bm; const float* bias; int col0; int mat = 0;
  if (EPI == 0) {
    mat  = bn / 8;                               // 0=Q 1=K 2=V (768/96 = 8 bn each)
    Bm   = (mat == 0) ? B0 : (mat == 1) ? B1 : B2;
    bias = (mat == 0) ? bias0 : (mat == 1) ? bias1 : bias2;
    col0 = (bn % 8) * TN;
  } else {
    Bm = B0; bias = bias0; col0 = bn * TN;
  }
  const int wr = w >> 1, wc = w & 1;

  f32x4 acc[MF][NF] = {};

#define GSTAGE(BUF, K0) do {                                                  \
    _Pragma("unroll")                                                         \
    for (int c = w; c < TM/16; c += 4) {                                      \
      const int a = c*1024 + lane*16;                                         \
      gl_lds16((const char*)A + ((size_t)(row0 + (a>>6))*DM + (K0))*2 + (a&63), \
               (char*)At[BUF] + c*1024);                                      \
    }                                                                         \
    _Pragma("unroll")                                                         \
    for (int c = w; c < TN/16; c += 4) {                                      \
      const int a = c*1024 + lane*16;                                         \
      gl_lds16((const char*)Bm + ((size_t)(col0 + (a>>6))*DM + (K0))*2 + (a&63), \
               (char*)Bt[BUF] + c*1024);                                      \
    }                                                                         \
  } while (0)

  GSTAGE(0, 0);
  GSTAGE(1, 32);
  int cur = 0;
  const int nsteps = DM / 32;                    // 24
#pragma unroll 1
  for (int j = 0; j < nsteps; ++j) {
    if (j + 1 < nsteps) {
      if constexpr (TM == 128) asm volatile("s_waitcnt vmcnt(3)" ::: "memory");
      else                     asm volatile("s_waitcnt vmcnt(2)" ::: "memory");
    } else {
      asm volatile("s_waitcnt vmcnt(0)" ::: "memory");
    }
    __builtin_amdgcn_s_barrier();
    __builtin_amdgcn_sched_barrier(0);
    if (j + 2 < nsteps) {
      int nb = cur + 2; if (nb >= 3) nb -= 3;
      GSTAGE(nb, (j + 2) * 32);
    }

    bf16x8 fa[MF], fb[NF];
#pragma unroll
    for (int m = 0; m < MF; ++m)
      fa[m] = ldbf8(&At[cur][(wr*(TM/2) + m*16 + ll)*32 + lg*8]);
#pragma unroll
    for (int n = 0; n < NF; ++n)
      fb[n] = ldbf8(&Bt[cur][(wc*(TN/2) + n*16 + ll)*32 + lg*8]);
#pragma unroll
    for (int m = 0; m < MF; ++m)
#pragma unroll
      for (int n = 0; n < NF; ++n)
        acc[m][n] = __builtin_amdgcn_mfma_f32_16x16x32_bf16(fa[m], fb[n], acc[m][n], 0, 0, 0);
    cur = (cur == 2) ? 0 : cur + 1;
  }
#undef GSTAGE

#pragma unroll
  for (int m = 0; m < MF; ++m) {
#pragma unroll
    for (int n = 0; n < NF; ++n) {
      const int gn  = col0 + wc*(TN/2) + n*16 + ll;
      const float bv = bias[gn];
      const int gm0 = row0 + wr*(TM/2) + m*16 + lg*4;
#pragma unroll
      for (int j = 0; j < 4; ++j) {
        const float v = acc[m][n][j] + bv;
        const int gm = gm0 + j;
        if (EPI == 0) {
          const int b = gm >> 11, s = gm & 2047;
          const int h = gn >> 6,  d = gn & 63;
          const size_t bh = (size_t)(b*NH + h);
          if (mat == 0)      q_out[(bh*SEQ + s)*DK + d] = f2bf(v * QSCALE);
          else if (mat == 1) k_out[(bh*SEQ + s)*DK + d] = f2bf(v);
          else               vt_out[(bh*DK + d)*SEQ + s] = f2bf(v);
        } else {
          f_out[(size_t)gm*DM + gn] = v;
        }
      }
    }
  }
}

// ---------------- flash attention (R14: single-buffered KV, 3 blocks/CU) ----
__device__ __forceinline__ void stage_kv(const u16* kp, const u16* vp, int kv0,
                                         u16* Kb, u16* Vb, int r, int lane) {
  const char* kg = (const char*)kp + (size_t)kv0 * 128;   // K rows contiguous
  const char* vg = (const char*)vp + (size_t)kv0 * 2;     // V^T rows stride 4096B
#pragma unroll
  for (int j = 0; j < 4; ++j) {
    const int base = (r*4 + j) * 1024;          // wave-uniform base; HW adds lane*16
    const int a = base + lane*16;
    const int row = a >> 7;                     // 128B rows
    const int cs  = ((a >> 4) & 7) ^ (row & 7); // inverse-swizzled source chunk
    gl_lds16(kg + row*128 + cs*16, (char*)Kb + base);
    gl_lds16(vg + (size_t)row*4096 + cs*16, (char*)Vb + base);
  }
}

__device__ __forceinline__ bf16x8 ldtile(const u16* T, int row, int wo) {
  // swizzled read of 16B at logical (row, byte-offset wo) from a [64][64] bf16 tile
  return ldbf8((const u16*)((const char*)T + row*128 + (wo ^ ((row & 7) << 4))));
}

__global__ __launch_bounds__(256, 3) void attn_fwd(
    const u16* __restrict__ qb, const u16* __restrict__ kb,
    const u16* __restrict__ vtb, u16* __restrict__ attb)
{
  __shared__ u16 KVb[2][2][64*64];              // [parity][K|V] = 32KB (single buf)
  __shared__ __align__(16) char arena[9216];    // P repack (loop) / merge (epilogue)
  const int L = blockIdx.x;
  const int xcd = L & 7, rr0 = L >> 3;
  const int bh = xcd * 3 + (rr0 % 3);            // XCD-clustered: 3 bh per XCD
  const int pairb = rr0 / 3;                     // 0..31
  const int tid = threadIdx.x;
  const int w = tid >> 6, lane = tid & 63;
  const int r = w & 1, h = w >> 1;               // row-chunk, KV-parity
  const int lg = lane >> 4, ll = lane & 15;
  const u16* qp = qb  + (size_t)bh * SEQ * DK;
  const u16* kp = kb  + (size_t)bh * SEQ * DK;
  const u16* vp = vtb + (size_t)bh * DK * SEQ;
  const int b = bh / NH, hh = bh % NH;
  u16* Pl = (u16*)(arena + w*2304);              // 16 rows x 72 u16 per wave
  float* mg = (float*)(arena + r*4608) + lane*18;

#pragma unroll 1
  for (int half = 0; half < 2; ++half) {
    const int tile = half ? pairb : 63 - pairb;  // 32-row q-tiles, balanced pair
    const int nt = (tile >> 1) + 1;              // KV tiles needed (causal)
    const int q0 = tile * 32 + r * 16;

    const bf16x8 qf0 = ldbf8(&qp[(size_t)(q0 + ll)*DK + lg*8]);
    const bf16x8 qf1 = ldbf8(&qp[(size_t)(q0 + ll)*DK + 32 + lg*8]);

    f32x4 o[4] = {};                             // lane holds O[q0+ll][dt*16+lg*4+j]
    float mrun = 0.f, lrun = 0.f;                // m=0 valid: defer-thr bounds P<=2^8

    const int nI = (nt + 1) >> 1;                // windows (= parity-0 tile count)
    if (h < nt) stage_kv(kp, vp, h*64, KVb[h][0], KVb[h][1], r, lane);

#pragma unroll 1
    for (int i = 0; i < nI; ++i) {
      const int t = h + 2*i;                     // this parity's tile
      asm volatile("s_waitcnt vmcnt(0)" ::: "memory");   // own stage drained
      __builtin_amdgcn_s_barrier();              // all waves' stage landed
      __builtin_amdgcn_sched_barrier(0);

      if (t < nt) {
        const u16* Kc = KVb[h][0];
        const u16* Vc = KVb[h][1];

        // S^T = K . Q^T over d=64
        f32x4 st[4] = {};
        __builtin_amdgcn_s_setprio(1);
#pragma unroll
        for (int kt = 0; kt < 4; ++kt) {
          const int rr = kt*16 + ll;
          st[kt] = __builtin_amdgcn_mfma_f32_16x16x32_bf16(ldtile(Kc, rr, lg*16),      qf0, st[kt], 0,0,0);
          st[kt] = __builtin_amdgcn_mfma_f32_16x16x32_bf16(ldtile(Kc, rr, 64 + lg*16), qf1, st[kt], 0,0,0);
        }
        __builtin_amdgcn_s_setprio(0);
        if (t == nt - 1) {                       // diagonal tile: causal mask
          const int kvb = t*64;
#pragma unroll
          for (int kt = 0; kt < 4; ++kt)
#pragma unroll
            for (int j = 0; j < 4; ++j)
              if (kvb + kt*16 + lg*4 + j > q0 + ll) st[kt][j] = -1e30f;
        }

        float lm = -1e30f;
#pragma unroll
        for (int kt = 0; kt < 4; ++kt)
          lm = fmaxf(lm, fmaxf(fmaxf(st[kt][0], st[kt][1]), fmaxf(st[kt][2], st[kt][3])));

        if (!__all(lm <= mrun + 8.f)) {          // rare: real max growth -> rescale
          float mt = lm;
          mt = fmaxf(mt, __shfl_xor(mt, 16));
          mt = fmaxf(mt, __shfl_xor(mt, 32));
          const float mn = fmaxf(mrun, mt);
          const float sc = exp2f(mrun - mn);
          lrun *= sc;
#pragma unroll
          for (int dt = 0; dt < 4; ++dt)
#pragma unroll
            for (int j = 0; j < 4; ++j)
              o[dt][j] *= sc;
          mrun = mn;
        }

        float psum = 0.f;
        unsigned pd[8];
#pragma unroll
        for (int kt = 0; kt < 4; ++kt) {
          const float e0 = exp2f(st[kt][0] - mrun);
          const float e1 = exp2f(st[kt][1] - mrun);
          const float e2 = exp2f(st[kt][2] - mrun);
          const float e3 = exp2f(st[kt][3] - mrun);
          psum += (e0 + e1) + (e2 + e3);
          pd[kt*2]   = cvtpk(e0, e1);
          pd[kt*2+1] = cvtpk(e2, e3);
        }
        lrun += psum;                            // per-lane partial (own k-chunks)

        // P repack (same-wave LDS round-trip; DS in-order within wave)
#pragma unroll
        for (int kt = 0; kt < 4; ++kt)
          *(uint2*)&Pl[ll*72 + kt*16 + lg*4] = make_uint2(pd[kt*2], pd[kt*2+1]);
        const bf16x8 pb0 = ldbf8(&Pl[ll*72 + lg*8]);
        const bf16x8 pb1 = ldbf8(&Pl[ll*72 + 32 + lg*8]);

        // O^T += V^T . P^T
        __builtin_amdgcn_s_setprio(1);
#pragma unroll
        for (int dt = 0; dt < 4; ++dt) {
          const int rr = dt*16 + ll;
          o[dt] = __builtin_amdgcn_mfma_f32_16x16x32_bf16(ldtile(Vc, rr, lg*16),      pb0, o[dt], 0,0,0);
          o[dt] = __builtin_amdgcn_mfma_f32_16x16x32_bf16(ldtile(Vc, rr, 64 + lg*16), pb1, o[dt], 0,0,0);
        }
        __builtin_amdgcn_s_setprio(0);
      }

      __builtin_amdgcn_s_barrier();              // ALL waves' reads of KVb done
      if (t + 2 < nt)                            // restage same buffer for t+2
        stage_kv(kp, vp, (t+2)*64, KVb[h][0], KVb[h][1], r, lane);
    }

    // per-parity row totals (row-uniform across the 4 lane-groups)
    float lt = lrun;
    lt += __shfl_xor(lt, 16);
    lt += __shfl_xor(lt, 32);

    // merge parity partials through arena: h=1 publishes, h=0 merges + stores
    __syncthreads();                             // all P-reads done; arena reusable
    if (h == 1) {
#pragma unroll
      for (int dt = 0; dt < 4; ++dt)
#pragma unroll
        for (int j = 0; j < 4; ++j)
          mg[dt*4 + j] = o[dt][j];
      mg[16] = mrun;
      mg[17] = lt;
    }
    __syncthreads();
    if (h == 0) {
      const float mB = mg[16], lB = mg[17];
      const float ms = fmaxf(mrun, mB);
      const float sA = exp2f(mrun - ms), sB = exp2f(mB - ms);
      const float li = 1.0f / (lt * sA + lB * sB);
      u16* orow = &attb[(size_t)(b*SEQ + q0 + ll)*DM + hh*64];
#pragma unroll
      for (int dt = 0; dt < 4; ++dt) {
        ushort4 rw;
        rw.x = f2bf((o[dt][0]*sA + mg[dt*4+0]*sB) * li);
        rw.y = f2bf((o[dt][1]*sA + mg[dt*4+1]*sB) * li);
        rw.z = f2bf((o[dt][2]*sA + mg[dt*4+2]*sB) * li);
        rw.w = f2bf((o[dt][3]*sA + mg[dt*4+3]*sB) * li);
        *(ushort4*)&orow[dt*16 + lg*4] = rw;
      }
    }
    __syncthreads();                             // arena free before next half
  }
}

// ---------------- launch ----------------
extern "C" void kernel_launch(void* const* d_in, const int* in_sizes, int n_in,
                              void* d_out, int out_size, void* d_ws, size_t ws_size,
                              hipStream_t stream) {
  const float* x  = (const float*)d_in[0];
  const float* wq = (const float*)d_in[1];
  const float* bq = (const float*)d_in[2];
  const float* wk = (const float*)d_in[3];
  const float* bk = (const float*)d_in[4];
  const float* wv = (const float*)d_in[5];
  const float* bv = (const float*)d_in[6];
  const float* wo = (const float*)d_in[7];
  const float* bo = (const float*)d_in[8];
  float* out = (float*)d_out;

  char* ws = (char*)d_ws;
  u16* xb   = (u16*)(ws);               // [4096][768]
  u16* wqb  = (u16*)(ws + 6291456);     // [768][768] x4 contiguous (wq,wk,wv,wo)
  u16* wkb  = (u16*)(ws + 7471104);
  u16* wvb  = (u16*)(ws + 8650752);
  u16* wob  = (u16*)(ws + 9830400);
  u16* qb   = (u16*)(ws + 11010048);    // [24][2048][64] scaled
  u16* kb   = (u16*)(ws + 17301504);    // [24][2048][64]
  u16* vtb  = (u16*)(ws + 23592960);    // [24][64][2048]
  u16* attb = (u16*)(ws + 29884416);    // [4096][768]

  const int nx4 = MROWS*DM/4;           // 786432
  const int nw4 = DM*DM/4;              // 147456
  const int ntot = nx4 + 4*nw4;         // 1376256 = 5376 * 256
  cvt_all<<<ntot/256, 256, 0, stream>>>(x, wq, wk, wv, wo, xb, wqb, nx4, nw4);

  gemm_bt<0,128><<<768, 256, 0, stream>>>(xb, wqb, wkb, wvb, bq, bk, bv,
                                          qb, kb, vtb, nullptr);
  attn_fwd<<<768, 256, 0, stream>>>(qb, kb, vtb, attb);
  gemm_bt<1,64><<<512, 256, 0, stream>>>(attb, wob, nullptr, nullptr, bo, nullptr, nullptr,
                                         nullptr, nullptr, nullptr, out);
}

// Round 16
// 92.051 us; speedup vs baseline: 1.3846x; 1.0130x over previous
//
#include <hip/hip_runtime.h>

// MHA forward, MI355X gfx950. bf16 MFMA pipeline, fp32 accumulate.
// R16: R15 GEMMs + attention v16: 4-wave blocks = 2 q-chunks x 2 kv-halves
//      over ONE shared single-buffered KV tile (16KB). 1536 blocks, 25.6KB
//      LDS -> 6 blocks/CU, 24 waves/CU (2x TLP vs R15). In-block 2-way
//      kv-half merge (R10-proven math).

#define DM   768
#define SEQ  2048
#define NB   2
#define NH   12
#define DK   64
#define MROWS (NB*SEQ)                       // 4096
#define QSCALE 0.18033688011112042f          // (1/sqrt(64)) * log2(e): softmax in exp2 domain

typedef unsigned short u16;
typedef __bf16 bf16x8 __attribute__((ext_vector_type(8)));
typedef float  f32x4  __attribute__((ext_vector_type(4)));
typedef unsigned int u32x4 __attribute__((ext_vector_type(4)));

__device__ __forceinline__ u16 f2bf(float f) {      // RNE f32 -> bf16
  unsigned u = __builtin_bit_cast(unsigned, f);
  u += 0x7fffu + ((u >> 16) & 1u);
  return (u16)(u >> 16);
}

__device__ __forceinline__ unsigned cvtpk(float lo, float hi) {  // 2xbf16 pack, RNE
  unsigned r;
  asm("v_cvt_pk_bf16_f32 %0, %1, %2" : "=v"(r) : "v"(lo), "v"(hi));
  return r;
}

__device__ __forceinline__ bf16x8 ldbf8(const u16* p) {   // 16B aligned load
  return __builtin_bit_cast(bf16x8, *(const u32x4*)p);
}

__device__ __forceinline__ void gl_lds16(const void* g, void* l) {
  __builtin_amdgcn_global_load_lds((__attribute__((address_space(1))) void*)g,
                                   (__attribute__((address_space(3))) void*)l,
                                   16, 0, 0);
}

// ---------------- fp32 -> bf16 convert, single launch (x + 4 weights) -------
__global__ void cvt_all(const float* __restrict__ x,
                        const float* __restrict__ w0, const float* __restrict__ w1,
                        const float* __restrict__ w2, const float* __restrict__ w3,
                        u16* __restrict__ dx, u16* __restrict__ dw,
                        int nx4, int nw4) {
  const int i = blockIdx.x * blockDim.x + threadIdx.x;
  const float* s; ushort4* d; int idx;
  if (i < nx4) {
    s = x; d = (ushort4*)dx; idx = i;
  } else {
    const int j = i - nx4;
    const int m = j / nw4;
    idx = j - m * nw4;
    s = (m == 0) ? w0 : (m == 1) ? w1 : (m == 2) ? w2 : w3;
    d = (ushort4*)dw + (size_t)m * nw4;
  }
  const float4 v = ((const float4*)s)[idx];
  ushort4 rr;
  rr.x = f2bf(v.x); rr.y = f2bf(v.y); rr.z = f2bf(v.z); rr.w = f2bf(v.w);
  d[idx] = rr;
}

// ---------------- gemm_bt: C[m][n] = sum_k A[m][k]*B[n][k] (R15) ------------
template <int EPI, int TM>
__global__ __launch_bounds__(256, 3) void gemm_bt(
    const u16* __restrict__ A,
    const u16* __restrict__ B0, const u16* __restrict__ B1, const u16* __restrict__ B2,
    const float* __restrict__ bias0, const float* __restrict__ bias1, const float* __restrict__ bias2,
    u16* __restrict__ q_out, u16* __restrict__ k_out, u16* __restrict__ vt_out,
    float* __restrict__ f_out)
{
  constexpr int TN = 96;
  constexpr int MF = TM / 32;
  constexpr int NF = TN / 32;
  __shared__ u16 At[3][TM*32];
  __shared__ u16 Bt[3][TN*32];
  const int tid = threadIdx.x;
  const int w = tid >> 6, lane = tid & 63;
  const int lg = lane >> 4, ll = lane & 15;

  const int L = blockIdx.x;
  const int xcd = L & 7, li = L >> 3;
  int bm, bn;
  if (EPI == 0) { bm = xcd*4 + li/24; bn = li%24; }    // 32 bm, 24 bn
  else          { bm = xcd*8 + li/8;  bn = li%8;  }    // 64 bm, 8 bn
  const int row0 = bm * TM;

  const u16* Bm; const float* bias; int col0; int mat = 0;
  if (EPI == 0) {
    mat  = bn / 8;                               // 0=Q 1=K 2=V
    Bm   = (mat == 0) ? B0 : (mat == 1) ? B1 : B2;
    bias = (mat == 0) ? bias0 : (mat == 1) ? bias1 : bias2;
    col0 = (bn % 8) * TN;
  } else {
    Bm = B0; bias = bias0; col0 = bn * TN;
  }
  const int wr = w >> 1, wc = w & 1;

  f32x4 acc[MF][NF] = {};

#define GSTAGE(BUF, K0) do {                                                  \
    _Pragma("unroll")                                                         \
    for (int c = w; c < TM/16; c += 4) {                                      \
      const int a = c*1024 + lane*16;                                         \
      gl_lds16((const char*)A + ((size_t)(row0 + (a>>6))*DM + (K0))*2 + (a&63), \
               (char*)At[BUF] + c*1024);                                      \
    }                                                                         \
    _Pragma("unroll")                                                         \
    for (int c = w; c < TN/16; c += 4) {                                      \
      const int a = c*1024 + lane*16;                                         \
      gl_lds16((const char*)Bm + ((size_t)(col0 + (a>>6))*DM + (K0))*2 + (a&63), \
               (char*)Bt[BUF] + c*1024);                                      \
    }                                                                         \
  } while (0)

  GSTAGE(0, 0);
  GSTAGE(1, 32);
  int cur = 0;
  const int nsteps = DM / 32;                    // 24
#pragma unroll 1
  for (int j = 0; j < nsteps; ++j) {
    if (j + 1 < nsteps) {
      if constexpr (TM == 128) asm volatile("s_waitcnt vmcnt(3)" ::: "memory");
      else                     asm volatile("s_waitcnt vmcnt(2)" ::: "memory");
    } else {
      asm volatile("s_waitcnt vmcnt(0)" ::: "memory");
    }
    __builtin_amdgcn_s_barrier();
    __builtin_amdgcn_sched_barrier(0);
    if (j + 2 < nsteps) {
      int nb = cur + 2; if (nb >= 3) nb -= 3;
      GSTAGE(nb, (j + 2) * 32);
    }

    bf16x8 fa[MF], fb[NF];
#pragma unroll
    for (int m = 0; m < MF; ++m)
      fa[m] = ldbf8(&At[cur][(wr*(TM/2) + m*16 + ll)*32 + lg*8]);
#pragma unroll
    for (int n = 0; n < NF; ++n)
      fb[n] = ldbf8(&Bt[cur][(wc*(TN/2) + n*16 + ll)*32 + lg*8]);
#pragma unroll
    for (int m = 0; m < MF; ++m)
#pragma unroll
      for (int n = 0; n < NF; ++n)
        acc[m][n] = __builtin_amdgcn_mfma_f32_16x16x32_bf16(fa[m], fb[n], acc[m][n], 0, 0, 0);
    cur = (cur == 2) ? 0 : cur + 1;
  }
#undef GSTAGE

#pragma unroll
  for (int m = 0; m < MF; ++m) {
#pragma unroll
    for (int n = 0; n < NF; ++n) {
      const int gn  = col0 + wc*(TN/2) + n*16 + ll;
      const float bv = bias[gn];
      const int gm0 = row0 + wr*(TM/2) + m*16 + lg*4;
#pragma unroll
      for (int j = 0; j < 4; ++j) {
        const float v = acc[m][n][j] + bv;
        const int gm = gm0 + j;
        if (EPI == 0) {
          const int b = gm >> 11, s = gm & 2047;
          const int h = gn >> 6,  d = gn & 63;
          const size_t bh = (size_t)(b*NH + h);
          if (mat == 0)      q_out[(bh*SEQ + s)*DK + d] = f2bf(v * QSCALE);
          else if (mat == 1) k_out[(bh*SEQ + s)*DK + d] = f2bf(v);
          else               vt_out[(bh*DK + d)*SEQ + s] = f2bf(v);
        } else {
          f_out[(size_t)gm*DM + gn] = v;
        }
      }
    }
  }
}

// ---------------- flash attention v16: shared tile, kv-split waves ----------
// grid 1536 = 8 XCD x 3 bh x 64 q-tiles (deep-first). Block = 4 waves:
// c = w&1 q-chunk (16 rows), r = w>>1 kv-half (32 kv). ONE shared KV tile
// buffer (16KB), single-buffered; all 4 waves stage 4KB each per window.
// Window: vmcnt(0)+barrier (staged) -> compute (4 QK MFMA + softmax-half +
// 4 PV MFMA per wave) -> barrier -> stage(t+1). 25.6KB LDS -> 6 blocks/CU =
// 24 waves/CU (2x R15's TLP), all 1536 blocks resident. kv-half partials
// merged in-block through arena (2 sequential publish/merge phases).

__device__ __forceinline__ bf16x8 ldtile(const u16* T, int row, int wo) {
  // swizzled 16B read at logical (row, byte-offset wo) of a [64][128B] LDS tile
  return ldbf8((const u16*)((const char*)T + row*128 + (wo ^ ((row & 7) << 4))));
}

__global__ __launch_bounds__(256, 6) void attn_fwd(
    const u16* __restrict__ qb, const u16* __restrict__ kb,
    const u16* __restrict__ vtb, u16* __restrict__ attb)
{
  __shared__ u16 Kt[64*64];                     // 8KB (kv rows x d cols)
  __shared__ u16 Vt[64*64];                     // 8KB (d rows x s cols)
  __shared__ __align__(16) char arena[9216];    // Pl 4x2304 (loop) / merge 4608 (epi)
  const int L = blockIdx.x;
  const int xcd = L & 7, li = L >> 3;            // li 0..191
  const int bh = xcd*3 + (li % 3);               // XCD-clustered: 3 bh per XCD
  const int tile = 63 - li/3;                    // deep-first
  const int tid = threadIdx.x;
  const int w = tid >> 6, lane = tid & 63;
  const int c = w & 1, r = w >> 1;               // q-chunk, kv-half
  const int lg = lane >> 4, ll = lane & 15;
  const u16* qp = qb  + (size_t)bh * SEQ * DK;
  const u16* kp = kb  + (size_t)bh * SEQ * DK;
  const u16* vp = vtb + (size_t)bh * DK * SEQ;
  const int bb = bh / NH, hh = bh % NH;
  const int nt = (tile >> 1) + 1;                // KV tiles (causal)
  const int q0 = tile*32 + c*16;
  u16* Pl = (u16*)(arena + w*2304);              // 16 rows x 72 u16 per wave
  float* mg = (float*)(arena) + lane*18;         // merge slot (epilogue only)

  const bf16x8 qf0 = ldbf8(&qp[(size_t)(q0 + ll)*DK + lg*8]);
  const bf16x8 qf1 = ldbf8(&qp[(size_t)(q0 + ll)*DK + 32 + lg*8]);

  f32x4 o[4] = {};                               // lane: O[q0+ll][dt*16+lg*4+j] (own kv-half)
  float mrun = 0.f, lrun = 0.f;                  // m=0 valid: defer-thr bounds P<=2^8

  // wave w stages 4 x 1KB chunks: w<2 -> K chunks w*4..+3; else V chunks
#define STAGE1(T) do {                                                        \
    const char* kg_ = (const char*)kp + (size_t)(T) * 64 * 128;               \
    const char* vg_ = (const char*)vp + (size_t)(T) * 128;                    \
    _Pragma("unroll")                                                         \
    for (int j2 = 0; j2 < 4; ++j2) {                                          \
      if (w < 2) {                                                            \
        const int base = (w*4 + j2) * 1024;                                   \
        const int a = base + lane*16;                                         \
        const int row = a >> 7;                                               \
        const int cs = ((a >> 4) & 7) ^ (row & 7);                            \
        gl_lds16(kg_ + row*128 + cs*16, (char*)Kt + base);                    \
      } else {                                                                \
        const int base = ((w-2)*4 + j2) * 1024;                               \
        const int a = base + lane*16;                                         \
        const int row = a >> 7;                                               \
        const int cs = ((a >> 4) & 7) ^ (row & 7);                            \
        gl_lds16(vg_ + (size_t)row*4096 + cs*16, (char*)Vt + base);           \
      }                                                                       \
    }                                                                         \
  } while (0)

  STAGE1(0);

#pragma unroll 1
  for (int t = 0; t < nt; ++t) {
    asm volatile("s_waitcnt vmcnt(0)" ::: "memory");   // own stage drained
    __builtin_amdgcn_s_barrier();                // all waves' stage landed
    __builtin_amdgcn_sched_barrier(0);

    // S^T = K_half . Q^T over d=64 (4 MFMA)
    f32x4 st[2] = {};
    __builtin_amdgcn_s_setprio(1);
#pragma unroll
    for (int kt = 0; kt < 2; ++kt) {
      const int row = r*32 + kt*16 + ll;
      st[kt] = __builtin_amdgcn_mfma_f32_16x16x32_bf16(ldtile(Kt, row, lg*16),      qf0, st[kt], 0,0,0);
      st[kt] = __builtin_amdgcn_mfma_f32_16x16x32_bf16(ldtile(Kt, row, 64 + lg*16), qf1, st[kt], 0,0,0);
    }
    __builtin_amdgcn_s_setprio(0);

    if (t == nt - 1) {                           // diagonal tile: causal mask
      const int kvb = t*64 + r*32;
#pragma unroll
      for (int kt = 0; kt < 2; ++kt)
#pragma unroll
        for (int j = 0; j < 4; ++j)
          if (kvb + kt*16 + lg*4 + j > q0 + ll) st[kt][j] = -1e30f;
    }

    float lm = -1e30f;
#pragma unroll
    for (int kt = 0; kt < 2; ++kt)
      lm = fmaxf(lm, fmaxf(fmaxf(st[kt][0], st[kt][1]), fmaxf(st[kt][2], st[kt][3])));

    if (!__all(lm <= mrun + 8.f)) {              // rare: real max growth -> rescale
      float mt = lm;
      mt = fmaxf(mt, __shfl_xor(mt, 16));
      mt = fmaxf(mt, __shfl_xor(mt, 32));
      const float mn = fmaxf(mrun, mt);
      const float sc = exp2f(mrun - mn);
      lrun *= sc;
#pragma unroll
      for (int dt = 0; dt < 4; ++dt)
#pragma unroll
        for (int j = 0; j < 4; ++j)
          o[dt][j] *= sc;
      mrun = mn;
    }

    float psum = 0.f;
    unsigned pd[4];
#pragma unroll
    for (int kt = 0; kt < 2; ++kt) {
      const float e0 = exp2f(st[kt][0] - mrun);
      const float e1 = exp2f(st[kt][1] - mrun);
      const float e2 = exp2f(st[kt][2] - mrun);
      const float e3 = exp2f(st[kt][3] - mrun);
      psum += (e0 + e1) + (e2 + e3);
      pd[kt*2]   = cvtpk(e0, e1);
      pd[kt*2+1] = cvtpk(e2, e3);
    }
    lrun += psum;                                // per-lane partial (own kv subset)

    // P repack (same-wave LDS round-trip; DS in-order within wave)
#pragma unroll
    for (int kt = 0; kt < 2; ++kt)
      *(uint2*)&Pl[ll*72 + kt*16 + lg*4] = make_uint2(pd[kt*2], pd[kt*2+1]);
    const bf16x8 pb = ldbf8(&Pl[ll*72 + lg*8]);  // P[q=ll][k_local = lg*8..+7]

    // O^T += V_half^T . P^T (K-dim = 32, 4 MFMA)
    __builtin_amdgcn_s_setprio(1);
#pragma unroll
    for (int dt = 0; dt < 4; ++dt)
      o[dt] = __builtin_amdgcn_mfma_f32_16x16x32_bf16(
                ldtile(Vt, dt*16 + ll, r*64 + lg*16), pb, o[dt], 0,0,0);
    __builtin_amdgcn_s_setprio(0);

    __builtin_amdgcn_s_barrier();                // ALL waves' reads of Kt/Vt done
    if (t + 1 < nt) STAGE1(t + 1);               // restage same buffer
  }
#undef STAGE1

  // per-wave row totals over own kv-half (sum the 4 lane-groups)
  float lt = lrun;
  lt += __shfl_xor(lt, 16);
  lt += __shfl_xor(lt, 32);

  // merge kv-halves per chunk: (w0<-w2) chunk0, (w1<-w3) chunk1, f32 exact
#define PUBLISH() do {                                                   \
    _Pragma("unroll")                                                    \
    for (int dt = 0; dt < 4; ++dt)                                       \
      _Pragma("unroll")                                                  \
      for (int j = 0; j < 4; ++j)                                        \
        mg[dt*4 + j] = o[dt][j];                                         \
    mg[16] = mrun;                                                       \
    mg[17] = lt;                                                         \
  } while (0)
#define MERGE_STORE() do {                                               \
    const float mB = mg[16], lB = mg[17];                                \
    const float ms = fmaxf(mrun, mB);                                    \
    const float sA = exp2f(mrun - ms), sB = exp2f(mB - ms);              \
    const float li2 = 1.0f / (lt * sA + lB * sB);                        \
    u16* orow = &attb[(size_t)(bb*SEQ + q0 + ll)*DM + hh*64];            \
    _Pragma("unroll")                                                    \
    for (int dt = 0; dt < 4; ++dt) {                                     \
      ushort4 rw;                                                        \
      rw.x = f2bf((o[dt][0]*sA + mg[dt*4+0]*sB) * li2);                  \
      rw.y = f2bf((o[dt][1]*sA + mg[dt*4+1]*sB) * li2);                  \
      rw.z = f2bf((o[dt][2]*sA + mg[dt*4+2]*sB) * li2);                  \
      rw.w = f2bf((o[dt][3]*sA + mg[dt*4+3]*sB) * li2);                  \
      *(ushort4*)&orow[dt*16 + lg*4] = rw;                               \
    }                                                                    \
  } while (0)

  __syncthreads();                               // compute done; arena free
  if (w == 2) PUBLISH();
  __syncthreads();
  if (w == 0) MERGE_STORE();
  __syncthreads();
  if (w == 3) PUBLISH();
  __syncthreads();
  if (w == 1) MERGE_STORE();
#undef PUBLISH
#undef MERGE_STORE
}

// ---------------- launch ----------------
extern "C" void kernel_launch(void* const* d_in, const int* in_sizes, int n_in,
                              void* d_out, int out_size, void* d_ws, size_t ws_size,
                              hipStream_t stream) {
  const float* x  = (const float*)d_in[0];
  const float* wq = (const float*)d_in[1];
  const float* bq = (const float*)d_in[2];
  const float* wk = (const float*)d_in[3];
  const float* bk = (const float*)d_in[4];
  const float* wv = (const float*)d_in[5];
  const float* bv = (const float*)d_in[6];
  const float* wo = (const float*)d_in[7];
  const float* bo = (const float*)d_in[8];
  float* out = (float*)d_out;

  char* ws = (char*)d_ws;
  u16* xb   = (u16*)(ws);               // [4096][768]
  u16* wqb  = (u16*)(ws + 6291456);     // [768][768] x4 contiguous (wq,wk,wv,wo)
  u16* wkb  = (u16*)(ws + 7471104);
  u16* wvb  = (u16*)(ws + 8650752);
  u16* wob  = (u16*)(ws + 9830400);
  u16* qb   = (u16*)(ws + 11010048);    // [24][2048][64] scaled
  u16* kb   = (u16*)(ws + 17301504);    // [24][2048][64]
  u16* vtb  = (u16*)(ws + 23592960);    // [24][64][2048]
  u16* attb = (u16*)(ws + 29884416);    // [4096][768]

  const int nx4 = MROWS*DM/4;           // 786432
  const int nw4 = DM*DM/4;              // 147456
  const int ntot = nx4 + 4*nw4;         // 1376256 = 5376 * 256
  cvt_all<<<ntot/256, 256, 0, stream>>>(x, wq, wk, wv, wo, xb, wqb, nx4, nw4);

  gemm_bt<0,128><<<768, 256, 0, stream>>>(xb, wqb, wkb, wvb, bq, bk, bv,
                                          qb, kb, vtb, nullptr);
  attn_fwd<<<1536, 256, 0, stream>>>(qb, kb, vtb, attb);
  gemm_bt<1,64><<<512, 256, 0, stream>>>(attb, wob, nullptr, nullptr, bo, nullptr, nullptr,
                                         nullptr, nullptr, nullptr, out);
}